// Round 7
// baseline (22.745 us; speedup 1.0000x reference)
//
#include <hip/hip_runtime.h>
#include <math.h>

// Problem constants
#define B_  32
#define D_  64
#define L_  4096
#define E_  8
#define OC_ 32
#define LP_ 4094   // L - 2 (VALID conv, kernel 3)
#define TILE 128
#define NT   32    // tiles per batch (4096/128)

typedef __attribute__((ext_vector_type(8)))  short short8;
typedef __attribute__((ext_vector_type(16))) float float16;

// packed f32x2 -> bf16x2 (low = a, high = b) in ONE instruction
static __device__ __forceinline__ unsigned cvtpk(float a, float b) {
    unsigned r;
    asm("v_cvt_pk_bf16_f32 %0, %1, %2" : "=v"(r) : "v"(a), "v"(b));
    return r;
}
// tanh via hw exp + rcp: 1 - 2/(e^{2x}+1)   (~5 VALU ops, err ~1e-5)
static __device__ __forceinline__ float fast_tanh(float x) {
    float e = __expf(2.0f * x);
    return fmaf(-2.0f, __builtin_amdgcn_rcpf(e + 1.0f), 1.0f);
}

// ---------------------------------------------------------------------------
// ONE kernel, zero prep, zero launch gap.
// Block = (batch, 128-col L tile); 4 waves, one 32-col MFMA tile each.
// Per block (all overlapping the x-tile staging load latency):
//   - c1w staged coalesced -> LDS in MFMA A-fragment order (3x ds_write_b128)
//   - gates computed redundantly per wave (accumulate-on-the-fly, no spill)
//   - conv2 A-fragments built from L2-hot c2w
// Then: barrier -> conv1 12x mfma (A,B from LDS) -> fast tanh -> in-register
// half-wave swap -> conv2 2x mfma -> direct MFMA-layout stores.
// ---------------------------------------------------------------------------
__global__ __launch_bounds__(256, 4)
void fused_all(const float* __restrict__ x,
               const float* __restrict__ w_gate,  // [320][8]
               const float* __restrict__ c1w,     // [32][64][3]
               const float* __restrict__ c1b,     // [32]
               const float* __restrict__ c2w,     // [256][32]
               const float* __restrict__ c2b,     // [256]
               float* __restrict__ out)           // [B][32][4094]
{
    // xT: bf16 [130 rows(l)][64 c] pitch 128 B, XOR-swizzle (row&7)<<4
    __shared__ __align__(16) unsigned short xT[130 * 64];   // 16640 B
    // aFl: conv1 A-fragments, bf16 [12][64][8]               12288 B
    __shared__ __align__(16) unsigned short aFl[12 * 64 * 8];

    const int tid  = threadIdx.x;
    const int lane = tid & 63;
    const int wv   = tid >> 6;
    const int b    = blockIdx.x >> 5;
    const int l0   = (blockIdx.x & 31) << 7;
    const float* xb = x + (size_t)b * (D_ * L_);

    // ---- stage x tile: f32 [c][l] -> bf16 xT[l][c] (c-pairs packed) ----
    {
        const int c2 = tid >> 3;          // 0..31 channel pair
        const int jb = (tid & 7) << 2;
        const float* p0 = xb + (size_t)(2 * c2) * L_ + l0;
        const float* p1 = p0 + L_;
        #pragma unroll
        for (int jq = 0; jq < 4; ++jq) {
            int j = jq * 32 + jb;
            float4 v0 = *(const float4*)(p0 + j);
            float4 v1 = *(const float4*)(p1 + j);
            float e0[4] = {v0.x, v0.y, v0.z, v0.w};
            float e1[4] = {v1.x, v1.y, v1.z, v1.w};
            #pragma unroll
            for (int r = 0; r < 4; ++r) {
                int row = j + r;
                int off = (row * 128 + c2 * 4) ^ ((row & 7) << 4);
                *(unsigned*)((char*)xT + off) = cvtpk(e0[r], e1[r]);
            }
        }
        if (tid < 64) {  // halo rows 128,129
            int cc2 = tid >> 1, jj = tid & 1;
            int row = TILE + jj;
            int lg  = l0 + row;
            float f0 = 0.f, f1 = 0.f;
            if (lg < L_) {
                f0 = xb[(size_t)(2 * cc2) * L_ + lg];
                f1 = xb[(size_t)(2 * cc2 + 1) * L_ + lg];
            }
            int off = (row * 128 + cc2 * 4) ^ ((row & 7) << 4);
            *(unsigned*)((char*)xT + off) = cvtpk(f0, f1);
        }
    }

    // ---- stage c1w -> aFl (coalesced read, fragment-order b128 writes) ----
    // thread: oc = tid>>3, c-range [c0, c0+8), all 3 taps = 24 consecutive f32.
    // Fragment slot for (oc, c, t): kp = t*64+c; ks = kp>>4; half = (kp>>3)&1;
    // ii = kp&7; dest = ((ks*64) + half*32 + oc)*8 + ii.
    // With c0 % 8 == 0, the 8 j-values (same t) fill ii = 0..7 of ONE slot.
    {
        const int oc = tid >> 3;
        const int c0 = (tid & 7) << 3;
        const float* wp = c1w + oc * 192 + c0 * 3;
        float v[24];
        #pragma unroll
        for (int q = 0; q < 6; ++q)
            *(float4*)(v + 4 * q) = *(const float4*)(wp + 4 * q);
        const int ksoff = c0 >> 4;
        const int half  = (c0 >> 3) & 1;
        #pragma unroll
        for (int t = 0; t < 3; ++t) {
            union { short8 s8; unsigned u[4]; } w8;
            #pragma unroll
            for (int jj = 0; jj < 4; ++jj)
                w8.u[jj] = cvtpk(v[(2 * jj) * 3 + t], v[(2 * jj + 1) * 3 + t]);
            int base = ((t * 4 + ksoff) * 64 + half * 32 + oc) * 8;
            *(short8*)(aFl + base) = w8.s8;
        }
    }

    // ---- gates (redundant per wave; accumulate-on-the-fly, low regs) ----
    int i0, i1;
    float g0, g1;
    {
        const int d = lane;
        float part[E_];
        #pragma unroll
        for (int e = 0; e < E_; ++e) part[e] = 0.f;
        #pragma unroll
        for (int t = 0; t < 5; ++t) {
            float xvt = xb[(size_t)d * L_ + (L_ - 6) + t];
            const float* wgp = w_gate + (d * 5 + t) * E_;
            float4 wa = *(const float4*)wgp;
            float4 wb = *(const float4*)(wgp + 4);
            part[0] = fmaf(xvt, wa.x, part[0]);
            part[1] = fmaf(xvt, wa.y, part[1]);
            part[2] = fmaf(xvt, wa.z, part[2]);
            part[3] = fmaf(xvt, wa.w, part[3]);
            part[4] = fmaf(xvt, wb.x, part[4]);
            part[5] = fmaf(xvt, wb.y, part[5]);
            part[6] = fmaf(xvt, wb.z, part[6]);
            part[7] = fmaf(xvt, wb.w, part[7]);
        }
        #pragma unroll
        for (int off = 1; off < 64; off <<= 1) {
            #pragma unroll
            for (int e = 0; e < E_; ++e)
                part[e] += __shfl_xor(part[e], off, 64);
        }
        float m = part[0];
        #pragma unroll
        for (int e = 1; e < E_; ++e) m = fmaxf(m, part[e]);
        float p[E_], s = 0.f;
        #pragma unroll
        for (int e = 0; e < E_; ++e) { p[e] = expf(part[e] - m); s += p[e]; }
        float inv = 1.f / s;
        #pragma unroll
        for (int e = 0; e < E_; ++e) p[e] *= inv;

        i0 = 0;
        #pragma unroll
        for (int e = 1; e < E_; ++e) if (p[e] > p[i0]) i0 = e;
        i1 = (i0 == 0) ? 1 : 0;
        #pragma unroll
        for (int e = 0; e < E_; ++e) {
            if (e == i0) continue;
            if (p[e] > p[i1]) i1 = e;
        }
        const float v0 = p[i0], v1 = p[i1];
        const float den = v0 + v1 + 1e-6f;
        g0 = v0 / den;
        g1 = v1 / den;
    }

    const int cl = lane & 31;
    const int hi = lane >> 5;

    // ---- conv2 A-frags from L2-hot c2w (loads overlap staging latency) ----
    short8 a2[2];
    #pragma unroll
    for (int ks = 0; ks < 2; ++ks) {
        const float* q0 = c2w + (cl * E_ + i0) * OC_ + ks * 16 + hi * 8;
        const float* q1 = c2w + (cl * E_ + i1) * OC_ + ks * 16 + hi * 8;
        float4 u0a = *(const float4*)q0, u0b = *(const float4*)(q0 + 4);
        float4 u1a = *(const float4*)q1, u1b = *(const float4*)(q1 + 4);
        union { short8 s8; unsigned u[4]; } f;
        f.u[0] = cvtpk(fmaf(g0, u0a.x, g1 * u1a.x), fmaf(g0, u0a.y, g1 * u1a.y));
        f.u[1] = cvtpk(fmaf(g0, u0a.z, g1 * u1a.z), fmaf(g0, u0a.w, g1 * u1a.w));
        f.u[2] = cvtpk(fmaf(g0, u0b.x, g1 * u1b.x), fmaf(g0, u0b.y, g1 * u1b.y));
        f.u[3] = cvtpk(fmaf(g0, u0b.z, g1 * u1b.z), fmaf(g0, u0b.w, g1 * u1b.w));
        a2[ks] = f.s8;
    }

    __syncthreads();

    // ---- conv1: 12 x mfma_32x32x16_bf16, A and B from LDS ----
    const int cb = wv * 32;
    float16 acc = (float16)0.0f;
    #pragma unroll
    for (int t = 0; t < 3; ++t) {
        int row = cb + cl + t;
        int rb  = row * 128;
        int swz = (row & 7) << 4;
        #pragma unroll
        for (int q = 0; q < 4; ++q) {
            short8 af = *(const short8*)(aFl + ((t * 4 + q) * 64 + lane) * 8);
            int off = (rb + q * 32 + hi * 16) ^ swz;
            short8 bf = *(const short8*)((const char*)xT + off);
            acc = __builtin_amdgcn_mfma_f32_32x32x16_bf16(af, bf, acc, 0, 0, 0);
        }
    }

    // ---- bias + fast tanh ----
    float th[16];
    #pragma unroll
    for (int r = 0; r < 16; ++r) {
        int row = (r & 3) + 8 * (r >> 2) + 4 * hi;
        th[r] = fast_tanh(acc[r] + c1b[row]);
    }

    // ---- conv2 B-frags in-register via half-wave swap (lane ^ 32) ----
    unsigned x0a = hi ? cvtpk(th[0],  th[1])  : cvtpk(th[4],  th[5]);
    unsigned x0b = hi ? cvtpk(th[2],  th[3])  : cvtpk(th[6],  th[7]);
    unsigned x1a = hi ? cvtpk(th[8],  th[9])  : cvtpk(th[12], th[13]);
    unsigned x1b = hi ? cvtpk(th[10], th[11]) : cvtpk(th[14], th[15]);
    unsigned r0a = (unsigned)__shfl_xor((int)x0a, 32, 64);
    unsigned r0b = (unsigned)__shfl_xor((int)x0b, 32, 64);
    unsigned r1a = (unsigned)__shfl_xor((int)x1a, 32, 64);
    unsigned r1b = (unsigned)__shfl_xor((int)x1b, 32, 64);

    union U { short8 s8; unsigned u[4]; };
    U b0, b1;
    b0.u[0] = hi ? r0a : cvtpk(th[0], th[1]);
    b0.u[1] = hi ? r0b : cvtpk(th[2], th[3]);
    b0.u[2] = hi ? cvtpk(th[4], th[5]) : r0a;
    b0.u[3] = hi ? cvtpk(th[6], th[7]) : r0b;
    b1.u[0] = hi ? r1a : cvtpk(th[8], th[9]);
    b1.u[1] = hi ? r1b : cvtpk(th[10], th[11]);
    b1.u[2] = hi ? cvtpk(th[12], th[13]) : r1a;
    b1.u[3] = hi ? cvtpk(th[14], th[15]) : r1b;

    float16 acc2 = (float16)0.0f;
    acc2 = __builtin_amdgcn_mfma_f32_32x32x16_bf16(a2[0], b0.s8, acc2, 0, 0, 0);
    acc2 = __builtin_amdgcn_mfma_f32_32x32x16_bf16(a2[1], b1.s8, acc2, 0, 0, 0);

    // ---- direct stores; bias2 from L1-hot c2b (uniform per half-wave) ----
    int l = l0 + cb + cl;
    if (l < LP_) {
        float* ob = out + (size_t)b * (OC_ * (size_t)LP_) + l;
        #pragma unroll
        for (int r = 0; r < 16; ++r) {
            int row = (r & 3) + 8 * (r >> 2) + 4 * hi;
            float bb = fmaf(g0, c2b[row * E_ + i0], g1 * c2b[row * E_ + i1]);
            ob[(size_t)row * LP_] = acc2[r] + bb;
        }
    }
}

// ---------------------------------------------------------------------------
extern "C" void kernel_launch(void* const* d_in, const int* in_sizes, int n_in,
                              void* d_out, int out_size, void* d_ws, size_t ws_size,
                              hipStream_t stream)
{
    const float* x      = (const float*)d_in[0];
    const float* w_gate = (const float*)d_in[1];
    const float* c1w    = (const float*)d_in[2];
    const float* c1b    = (const float*)d_in[3];
    const float* c2w    = (const float*)d_in[4];
    const float* c2b    = (const float*)d_in[5];
    float* out = (float*)d_out;

    fused_all<<<B_ * NT, 256, 0, stream>>>(x, w_gate, c1w, c1b, c2w, c2b, out);
}